// Round 1
// baseline (143.026 us; speedup 1.0000x reference)
//
#include <hip/hip_runtime.h>
#include <math.h>

#define EPS 1e-8f
#define NPATCH 196      // patches per image (14*14)
#define HW 50176        // 224*224
#define NB 4
#define DIM 768
#define LOG2E 1.4426950408889634f

// ws layout (floats):
// [0..9]           gram (4x4 symmetric, order 00,01,02,03,11,12,13,22,23,33)
// [32 .. 32+784*4) Gq float4 per global patch gp (basis_j . qn[b,m])
// [4096..4879]     per-block partial sums from k_pixel (784 blocks)

__global__ __launch_bounds__(256) void k_gram(const float* __restrict__ pixw,
                                              const float* __restrict__ pixb,
                                              float* __restrict__ ws) {
    int t = threadIdx.x;
    float g[10] = {0,0,0,0,0,0,0,0,0,0};
    for (int dd = 0; dd < 3; ++dd) {
        int d = t + dd * 256;
        float w0 = pixw[d*3+0], w1 = pixw[d*3+1], w2 = pixw[d*3+2], b = pixb[d];
        g[0] = fmaf(w0, w0, g[0]); g[1] = fmaf(w0, w1, g[1]);
        g[2] = fmaf(w0, w2, g[2]); g[3] = fmaf(w0, b,  g[3]);
        g[4] = fmaf(w1, w1, g[4]); g[5] = fmaf(w1, w2, g[5]);
        g[6] = fmaf(w1, b,  g[6]); g[7] = fmaf(w2, w2, g[7]);
        g[8] = fmaf(w2, b,  g[8]); g[9] = fmaf(b,  b,  g[9]);
    }
    for (int off = 32; off; off >>= 1)
        for (int j = 0; j < 10; ++j) g[j] += __shfl_down(g[j], off);
    __shared__ float red[4][10];
    int wv = t >> 6, ln = t & 63;
    if (ln == 0) for (int j = 0; j < 10; ++j) red[wv][j] = g[j];
    __syncthreads();
    if (t < 10) ws[t] = red[0][t] + red[1][t] + red[2][t] + red[3][t];
}

// 4 patches per block; each thread owns 3 output dims (t, t+256, t+512).
__global__ __launch_bounds__(256) void k_patch(const float* __restrict__ x,
                                               const float* __restrict__ pixw,
                                               const float* __restrict__ pixb,
                                               const float* __restrict__ paw,
                                               const float* __restrict__ pab,
                                               float* __restrict__ ws) {
    __shared__ float lx[4][768];
    __shared__ float red[4][4][5];   // [wave][patch][stat]
    int t = threadIdx.x;
    int g0 = blockIdx.x * 4;

    // stage 4 x-patches into LDS
    for (int j = 0; j < 12; ++j) {
        int flat = j * 256 + t;
        int p = flat / 768, e = flat - p * 768;
        int gp = g0 + p;
        int b = gp / NPATCH, m = gp - b * NPATCH;
        int hp = m / 14, wpc = m - hp * 14;
        int c = e >> 8, rem = e & 255, pr = rem >> 4, q = rem & 15;
        lx[p][e] = x[((b * 3 + c) * 224 + hp * 16 + pr) * 224 + wpc * 16 + q];
    }
    __syncthreads();

    float acc[3][4];
    for (int dd = 0; dd < 3; ++dd)
        for (int p = 0; p < 4; ++p) acc[dd][p] = 0.0f;

    for (int k = 0; k < 768; k += 4) {
        float4 a[4];
        for (int p = 0; p < 4; ++p) a[p] = *(const float4*)&lx[p][k];
        for (int dd = 0; dd < 3; ++dd) {
            int d = t + dd * 256;
            float4 w = *(const float4*)&paw[d * 768 + k];
            for (int p = 0; p < 4; ++p) {
                float s = acc[dd][p];
                s = fmaf(w.x, a[p].x, s);
                s = fmaf(w.y, a[p].y, s);
                s = fmaf(w.z, a[p].z, s);
                s = fmaf(w.w, a[p].w, s);
                acc[dd][p] = s;
            }
        }
    }

    // per-thread stats: norm^2 and 4 basis dots per patch
    float n2[4] = {0,0,0,0};
    float dj[4][4] = {{0,0,0,0},{0,0,0,0},{0,0,0,0},{0,0,0,0}};
    for (int dd = 0; dd < 3; ++dd) {
        int d = t + dd * 256;
        float bw0 = pixw[d*3+0], bw1 = pixw[d*3+1], bw2 = pixw[d*3+2];
        float bb = pixb[d];
        float pbv = pab[d];
        for (int p = 0; p < 4; ++p) {
            float v = acc[dd][p] + pbv;
            n2[p]    = fmaf(v, v,  n2[p]);
            dj[p][0] = fmaf(bw0, v, dj[p][0]);
            dj[p][1] = fmaf(bw1, v, dj[p][1]);
            dj[p][2] = fmaf(bw2, v, dj[p][2]);
            dj[p][3] = fmaf(bb,  v, dj[p][3]);
        }
    }
    for (int off = 32; off; off >>= 1) {
        for (int p = 0; p < 4; ++p) {
            n2[p] += __shfl_down(n2[p], off);
            for (int j = 0; j < 4; ++j) dj[p][j] += __shfl_down(dj[p][j], off);
        }
    }
    int wv = t >> 6, ln = t & 63;
    if (ln == 0) {
        for (int p = 0; p < 4; ++p) {
            red[wv][p][0] = n2[p];
            for (int j = 0; j < 4; ++j) red[wv][p][j+1] = dj[p][j];
        }
    }
    __syncthreads();
    if (t < 4) {
        int p = t;
        float s[5];
        for (int j = 0; j < 5; ++j)
            s[j] = red[0][p][j] + red[1][p][j] + red[2][p][j] + red[3][p][j];
        float rq = 1.0f / fmaxf(sqrtf(s[0]), EPS);
        int gp = g0 + p;
        float4 out = make_float4(s[1]*rq, s[2]*rq, s[3]*rq, s[4]*rq);
        *(float4*)&ws[32 + gp*4] = out;
    }
}

// one pixel per thread; 784 blocks x 256 threads = 200704 pixels
__global__ __launch_bounds__(256) void k_pixel(const float* __restrict__ x,
                                               float* __restrict__ ws) {
    int t = threadIdx.x;
    int bid = blockIdx.x;
    int b = bid / NPATCH, loc = bid - b * NPATCH;
    int hw = loc * 256 + t;
    const float* xb = x + b * (3 * HW);
    float c0 = xb[hw], c1 = xb[hw + HW], c2 = xb[hw + 2*HW];

    float G0=ws[0],G1=ws[1],G2=ws[2],G3=ws[3],G4=ws[4];
    float G5=ws[5],G6=ws[6],G7=ws[7],G8=ws[8],G9=ws[9];
    // n2 = c^T Gram c with c=(c0,c1,c2,1)
    float n2 = G9;
    n2 = fmaf(G0, c0*c0, n2);
    n2 = fmaf(G4, c1*c1, n2);
    n2 = fmaf(G7, c2*c2, n2);
    float cross = fmaf(G1, c0*c1, fmaf(G2, c0*c2, fmaf(G5, c1*c2,
                  fmaf(G3, c0, fmaf(G6, c1, G8*c2)))));
    n2 = fmaf(2.0f, cross, n2);

    float rnp = 1.0f / fmaxf(sqrtf(n2), EPS);
    float es = 2.0f * rnp * LOG2E;         // exp(2*SIM) = exp2(es * dot)
    float a0 = c0 * es, a1 = c1 * es, a2 = c2 * es;

    const float4* gq = (const float4*)(ws + 32) + b * NPATCH;
    float sum = 0.0f;
    for (int m = 0; m < NPATCH; ++m) {
        float4 g = gq[m];
        float tt = fmaf(a0, g.x, fmaf(a1, g.y, fmaf(a2, g.z, es * g.w)));
        sum += exp2f(tt);
    }
    {   // subtract the diagonal (excluded) term
        int ne = hw % NPATCH;
        float4 g = gq[ne];
        float tt = fmaf(a0, g.x, fmaf(a1, g.y, fmaf(a2, g.z, es * g.w)));
        sum -= exp2f(tt);
    }

    for (int off = 32; off; off >>= 1) sum += __shfl_down(sum, off);
    __shared__ float red[4];
    int wv = t >> 6, ln = t & 63;
    if (ln == 0) red[wv] = sum;
    __syncthreads();
    if (t == 0) ws[4096 + bid] = red[0] + red[1] + red[2] + red[3];
}

// deterministic final reduction of 784 block partials + log
__global__ __launch_bounds__(256) void k_log(const float* __restrict__ ws,
                                             float* __restrict__ out) {
    int t = threadIdx.x;
    float sum = 0.0f;
    for (int j = t; j < 784; j += 256) sum += ws[4096 + j];
    for (int off = 32; off; off >>= 1) sum += __shfl_down(sum, off);
    __shared__ float red[4];
    int wv = t >> 6, ln = t & 63;
    if (ln == 0) red[wv] = sum;
    __syncthreads();
    if (t == 0) out[0] = logf(red[0] + red[1] + red[2] + red[3]);
}

extern "C" void kernel_launch(void* const* d_in, const int* in_sizes, int n_in,
                              void* d_out, int out_size, void* d_ws, size_t ws_size,
                              hipStream_t stream) {
    const float* x    = (const float*)d_in[0];
    const float* pixw = (const float*)d_in[1];
    const float* pixb = (const float*)d_in[2];
    const float* paw  = (const float*)d_in[3];
    const float* pab  = (const float*)d_in[4];
    float* ws  = (float*)d_ws;
    float* out = (float*)d_out;

    hipLaunchKernelGGL(k_gram,  dim3(1),   dim3(256), 0, stream, pixw, pixb, ws);
    hipLaunchKernelGGL(k_patch, dim3(196), dim3(256), 0, stream, x, pixw, pixb, paw, pab, ws);
    hipLaunchKernelGGL(k_pixel, dim3(784), dim3(256), 0, stream, x, ws);
    hipLaunchKernelGGL(k_log,   dim3(1),   dim3(256), 0, stream, ws, out);
}

// Round 2
// 102.922 us; speedup vs baseline: 1.3897x; 1.3897x over previous
//
#include <hip/hip_runtime.h>
#include <math.h>

#define EPS 1e-8f
#define NPATCH 196
#define HW 50176
#define LOG2E 1.4426950408889634f

// ws float offsets
#define GRAM_OFF 0      // 10 floats
#define C_OFF 12        // 4 floats
#define N2_OFF 64       // 784 floats
#define M_OFF 1024      // 768*4 floats, [k][4]
#define GQ_OFF 4096     // 784*4 floats, [gp][4]
#define PART_OFF 8192   // 784 floats
#define WB_OFF 16384    // ushort[589824] = 294912 float slots

static __device__ __forceinline__ float bf16_hi(unsigned u) {
    return __uint_as_float(u & 0xFFFF0000u);
}
static __device__ __forceinline__ float bf16_lo(unsigned u) {
    return __uint_as_float(u << 16);
}

// blocks 0..5: M[4][768] column dots (k-chunks of 128) + optional bf16 weight copy
// block 6: gram (10) + c[4]
__global__ __launch_bounds__(512) void k_prep(const float* __restrict__ pixw,
                                              const float* __restrict__ pixb,
                                              const float* __restrict__ paw,
                                              const float* __restrict__ pab,
                                              float* __restrict__ ws, int do_wb) {
    __shared__ float lds[4 * 128 * 4];
    int t = threadIdx.x;
    int bid = blockIdx.x;
    if (bid < 6) {
        int kl = t & 127;
        int k = bid * 128 + kl;
        int dh = __builtin_amdgcn_readfirstlane(t >> 7);  // 0..3, wave-uniform
        float m0 = 0.f, m1 = 0.f, m2 = 0.f, m3 = 0.f;
        const float* wp = paw + (size_t)(dh * 192) * 768 + k;
        const float* bw = pixw + dh * 192 * 3;
        const float* bb = pixb + dh * 192;
        unsigned short* wbp = (unsigned short*)(ws + WB_OFF);
        if (do_wb) {
            #pragma unroll 4
            for (int i = 0; i < 192; ++i) {
                float w = wp[(size_t)i * 768];
                float s0 = bw[i*3+0], s1 = bw[i*3+1], s2 = bw[i*3+2], s3 = bb[i];
                m0 = fmaf(s0, w, m0); m1 = fmaf(s1, w, m1);
                m2 = fmaf(s2, w, m2); m3 = fmaf(s3, w, m3);
                unsigned u = __float_as_uint(w);
                u += 0x8000u + ((u >> 16) & 1u);          // RNE to bf16
                wbp[(size_t)(dh * 192 + i) * 768 + k] = (unsigned short)(u >> 16);
            }
        } else {
            #pragma unroll 4
            for (int i = 0; i < 192; ++i) {
                float w = wp[(size_t)i * 768];
                float s0 = bw[i*3+0], s1 = bw[i*3+1], s2 = bw[i*3+2], s3 = bb[i];
                m0 = fmaf(s0, w, m0); m1 = fmaf(s1, w, m1);
                m2 = fmaf(s2, w, m2); m3 = fmaf(s3, w, m3);
            }
        }
        float* L = lds + (dh * 128 + kl) * 4;
        L[0] = m0; L[1] = m1; L[2] = m2; L[3] = m3;
        __syncthreads();
        if (t < 128) {
            int kk = bid * 128 + t;
            float4 o;
            o.x = lds[(0*128+t)*4+0] + lds[(1*128+t)*4+0] + lds[(2*128+t)*4+0] + lds[(3*128+t)*4+0];
            o.y = lds[(0*128+t)*4+1] + lds[(1*128+t)*4+1] + lds[(2*128+t)*4+1] + lds[(3*128+t)*4+1];
            o.z = lds[(0*128+t)*4+2] + lds[(1*128+t)*4+2] + lds[(2*128+t)*4+2] + lds[(3*128+t)*4+2];
            o.w = lds[(0*128+t)*4+3] + lds[(1*128+t)*4+3] + lds[(2*128+t)*4+3] + lds[(3*128+t)*4+3];
            *(float4*)&ws[M_OFF + kk*4] = o;
        }
    } else {
        float g[14];
        #pragma unroll
        for (int j = 0; j < 14; ++j) g[j] = 0.f;
        for (int d = t; d < 768; d += 512) {
            float w0 = pixw[d*3+0], w1 = pixw[d*3+1], w2 = pixw[d*3+2];
            float b = pixb[d], pb = pab[d];
            g[0] = fmaf(w0, w0, g[0]); g[1] = fmaf(w0, w1, g[1]);
            g[2] = fmaf(w0, w2, g[2]); g[3] = fmaf(w0, b,  g[3]);
            g[4] = fmaf(w1, w1, g[4]); g[5] = fmaf(w1, w2, g[5]);
            g[6] = fmaf(w1, b,  g[6]); g[7] = fmaf(w2, w2, g[7]);
            g[8] = fmaf(w2, b,  g[8]); g[9] = fmaf(b,  b,  g[9]);
            g[10] = fmaf(w0, pb, g[10]); g[11] = fmaf(w1, pb, g[11]);
            g[12] = fmaf(w2, pb, g[12]); g[13] = fmaf(b,  pb, g[13]);
        }
        #pragma unroll
        for (int off = 32; off; off >>= 1)
            #pragma unroll
            for (int j = 0; j < 14; ++j) g[j] += __shfl_down(g[j], off);
        int wv = t >> 6, ln = t & 63;
        float* red = lds;  // [8][14]
        if (ln == 0)
            for (int j = 0; j < 14; ++j) red[wv*14 + j] = g[j];
        __syncthreads();
        if (t < 14) {
            float s = 0.f;
            for (int w = 0; w < 8; ++w) s += red[w*14 + t];
            if (t < 10) ws[GRAM_OFF + t] = s;
            else        ws[C_OFF + (t - 10)] = s;
        }
    }
}

// grid 196: 4 patches/block. 8 waves = 4 dim-waves x 2 k-halves.
// x read via wave-uniform scalar loads; weights per-lane (bf16 or f32).
template<bool BF16W>
__global__ __launch_bounds__(512, 2) void k_n2(const float* __restrict__ x,
                                               const float* __restrict__ paw,
                                               const float* __restrict__ pab,
                                               float* __restrict__ ws) {
    __shared__ float lds[4 * 64 * 13];
    __shared__ float red2[4][4];
    int t = threadIdx.x;
    int lane = t & 63;
    int wv = __builtin_amdgcn_readfirstlane(t >> 6);
    int dw = wv & 3, kh = wv >> 2;
    int pg = blockIdx.x;

    const float* xbp[4];
    #pragma unroll
    for (int pp = 0; pp < 4; ++pp) {
        int gp = pg * 4 + pp;
        int b = gp / NPATCH, m = gp - b * NPATCH;
        int hp = m / 14, wq = m - hp * 14;
        xbp[pp] = x + (size_t)b * (3 * HW) + (hp * 16) * 224 + wq * 16;
    }
    int d0 = dw * 192 + lane;

    float acc[3][4];
    #pragma unroll
    for (int i = 0; i < 3; ++i)
        #pragma unroll
        for (int p = 0; p < 4; ++p) acc[i][p] = 0.f;

    const unsigned short* wb = (const unsigned short*)(ws + WB_OFF);

    int r0 = kh * 24;
    #pragma unroll 2
    for (int r = r0; r < r0 + 24; ++r) {
        int c = r >> 4, pr = r & 15, kb = r * 16;
        const float* rp0 = xbp[0] + c * HW + pr * 224;
        const float* rp1 = xbp[1] + c * HW + pr * 224;
        const float* rp2 = xbp[2] + c * HW + pr * 224;
        const float* rp3 = xbp[3] + c * HW + pr * 224;
        #pragma unroll
        for (int qh = 0; qh < 2; ++qh) {
            float wf[3][8];
            if (BF16W) {
                #pragma unroll
                for (int dd = 0; dd < 3; ++dd) {
                    uint4 u = *(const uint4*)(wb + (size_t)(d0 + dd * 64) * 768 + kb + qh * 8);
                    wf[dd][0] = bf16_lo(u.x); wf[dd][1] = bf16_hi(u.x);
                    wf[dd][2] = bf16_lo(u.y); wf[dd][3] = bf16_hi(u.y);
                    wf[dd][4] = bf16_lo(u.z); wf[dd][5] = bf16_hi(u.z);
                    wf[dd][6] = bf16_lo(u.w); wf[dd][7] = bf16_hi(u.w);
                }
            } else {
                #pragma unroll
                for (int dd = 0; dd < 3; ++dd) {
                    const float* wrow = paw + (size_t)(d0 + dd * 64) * 768 + kb + qh * 8;
                    float4 a = *(const float4*)(wrow);
                    float4 b2 = *(const float4*)(wrow + 4);
                    wf[dd][0] = a.x; wf[dd][1] = a.y; wf[dd][2] = a.z; wf[dd][3] = a.w;
                    wf[dd][4] = b2.x; wf[dd][5] = b2.y; wf[dd][6] = b2.z; wf[dd][7] = b2.w;
                }
            }
            const float* rpq0 = rp0 + qh * 8;
            const float* rpq1 = rp1 + qh * 8;
            const float* rpq2 = rp2 + qh * 8;
            const float* rpq3 = rp3 + qh * 8;
            #pragma unroll
            for (int q = 0; q < 8; ++q) {
                float x0 = rpq0[q], x1 = rpq1[q], x2 = rpq2[q], x3 = rpq3[q];
                acc[0][0] = fmaf(wf[0][q], x0, acc[0][0]);
                acc[1][0] = fmaf(wf[1][q], x0, acc[1][0]);
                acc[2][0] = fmaf(wf[2][q], x0, acc[2][0]);
                acc[0][1] = fmaf(wf[0][q], x1, acc[0][1]);
                acc[1][1] = fmaf(wf[1][q], x1, acc[1][1]);
                acc[2][1] = fmaf(wf[2][q], x1, acc[2][1]);
                acc[0][2] = fmaf(wf[0][q], x2, acc[0][2]);
                acc[1][2] = fmaf(wf[1][q], x2, acc[1][2]);
                acc[2][2] = fmaf(wf[2][q], x2, acc[2][2]);
                acc[0][3] = fmaf(wf[0][q], x3, acc[0][3]);
                acc[1][3] = fmaf(wf[1][q], x3, acc[1][3]);
                acc[2][3] = fmaf(wf[2][q], x3, acc[2][3]);
            }
        }
    }
    if (kh == 1) {
        float* L = lds + (dw * 64 + lane) * 13;
        #pragma unroll
        for (int i = 0; i < 3; ++i)
            #pragma unroll
            for (int p = 0; p < 4; ++p) L[i * 4 + p] = acc[i][p];
    }
    __syncthreads();
    if (kh == 0) {
        const float* L = lds + (dw * 64 + lane) * 13;
        float sq[4] = {0.f, 0.f, 0.f, 0.f};
        #pragma unroll
        for (int i = 0; i < 3; ++i) {
            float bias = pab[d0 + i * 64];
            #pragma unroll
            for (int p = 0; p < 4; ++p) {
                float v = acc[i][p] + L[i * 4 + p] + bias;
                sq[p] = fmaf(v, v, sq[p]);
            }
        }
        #pragma unroll
        for (int off = 32; off; off >>= 1)
            #pragma unroll
            for (int p = 0; p < 4; ++p) sq[p] += __shfl_down(sq[p], off);
        if (lane == 0)
            for (int p = 0; p < 4; ++p) red2[dw][p] = sq[p];
    }
    __syncthreads();
    if (t < 4) {
        float n2 = red2[0][t] + red2[1][t] + red2[2][t] + red2[3][t];
        ws[N2_OFF + pg * 4 + t] = n2;
    }
}

// grid 98 x 256: 8 patches/block, 32 lanes per patch: Gq = (M.x + c) / ||q||
__global__ __launch_bounds__(256) void k_dj(const float* __restrict__ x,
                                            float* __restrict__ ws) {
    int t = threadIdx.x;
    int p8 = t >> 5, l = t & 31;
    int gp = blockIdx.x * 8 + p8;
    int b = gp / NPATCH, m = gp - b * NPATCH;
    int hp = m / 14, wq = m - hp * 14;
    const float* xb = x + (size_t)b * (3 * HW) + (hp * 16) * 224 + wq * 16;
    float d0 = 0.f, d1 = 0.f, d2 = 0.f, d3 = 0.f;
    #pragma unroll 4
    for (int j = 0; j < 24; ++j) {
        int k = j * 32 + l;
        int c = k >> 8, pr = (k >> 4) & 15, q = k & 15;
        float xv = xb[c * HW + pr * 224 + q];
        float4 Mv = *(const float4*)&ws[M_OFF + k * 4];
        d0 = fmaf(Mv.x, xv, d0); d1 = fmaf(Mv.y, xv, d1);
        d2 = fmaf(Mv.z, xv, d2); d3 = fmaf(Mv.w, xv, d3);
    }
    #pragma unroll
    for (int off = 16; off; off >>= 1) {
        d0 += __shfl_down(d0, off, 32); d1 += __shfl_down(d1, off, 32);
        d2 += __shfl_down(d2, off, 32); d3 += __shfl_down(d3, off, 32);
    }
    if (l == 0) {
        float n2 = ws[N2_OFF + gp];
        float rq = 1.0f / fmaxf(sqrtf(n2), EPS);
        float4 o;
        o.x = (d0 + ws[C_OFF + 0]) * rq;
        o.y = (d1 + ws[C_OFF + 1]) * rq;
        o.z = (d2 + ws[C_OFF + 2]) * rq;
        o.w = (d3 + ws[C_OFF + 3]) * rq;
        *(float4*)&ws[GQ_OFF + gp * 4] = o;
    }
}

__global__ __launch_bounds__(256) void k_pixel(const float* __restrict__ x,
                                               float* __restrict__ ws) {
    int t = threadIdx.x;
    int bid = blockIdx.x;
    int b = bid / NPATCH, loc = bid - b * NPATCH;
    int hw = loc * 256 + t;
    const float* xb = x + (size_t)b * (3 * HW);
    float c0 = xb[hw], c1 = xb[hw + HW], c2 = xb[hw + 2 * HW];

    float G0 = ws[0], G1 = ws[1], G2 = ws[2], G3 = ws[3], G4 = ws[4];
    float G5 = ws[5], G6 = ws[6], G7 = ws[7], G8 = ws[8], G9 = ws[9];
    float n2 = G9;
    n2 = fmaf(G0, c0 * c0, n2);
    n2 = fmaf(G4, c1 * c1, n2);
    n2 = fmaf(G7, c2 * c2, n2);
    float cross = fmaf(G1, c0 * c1, fmaf(G2, c0 * c2, fmaf(G5, c1 * c2,
                  fmaf(G3, c0, fmaf(G6, c1, G8 * c2)))));
    n2 = fmaf(2.0f, cross, n2);

    float rnp = 1.0f / fmaxf(sqrtf(n2), EPS);
    float es = 2.0f * rnp * LOG2E;
    float a0 = c0 * es, a1 = c1 * es, a2 = c2 * es;

    const float4* gq = (const float4*)(ws + GQ_OFF) + b * NPATCH;
    float sum = 0.0f;
    for (int m = 0; m < NPATCH; ++m) {
        float4 g = gq[m];
        float tt = fmaf(a0, g.x, fmaf(a1, g.y, fmaf(a2, g.z, es * g.w)));
        sum += exp2f(tt);
    }
    {
        int ne = hw % NPATCH;
        float4 g = gq[ne];
        float tt = fmaf(a0, g.x, fmaf(a1, g.y, fmaf(a2, g.z, es * g.w)));
        sum -= exp2f(tt);
    }

    #pragma unroll
    for (int off = 32; off; off >>= 1) sum += __shfl_down(sum, off);
    __shared__ float red[4];
    int wvv = t >> 6, ln = t & 63;
    if (ln == 0) red[wvv] = sum;
    __syncthreads();
    if (t == 0) ws[PART_OFF + bid] = red[0] + red[1] + red[2] + red[3];
}

__global__ __launch_bounds__(256) void k_log(const float* __restrict__ ws,
                                             float* __restrict__ out) {
    int t = threadIdx.x;
    float sum = 0.0f;
    for (int j = t; j < 784; j += 256) sum += ws[PART_OFF + j];
    #pragma unroll
    for (int off = 32; off; off >>= 1) sum += __shfl_down(sum, off);
    __shared__ float red[4];
    int wv = t >> 6, ln = t & 63;
    if (ln == 0) red[wv] = sum;
    __syncthreads();
    if (t == 0) out[0] = logf(red[0] + red[1] + red[2] + red[3]);
}

extern "C" void kernel_launch(void* const* d_in, const int* in_sizes, int n_in,
                              void* d_out, int out_size, void* d_ws, size_t ws_size,
                              hipStream_t stream) {
    (void)in_sizes; (void)n_in; (void)out_size;
    const float* x    = (const float*)d_in[0];
    const float* pixw = (const float*)d_in[1];
    const float* pixb = (const float*)d_in[2];
    const float* paw  = (const float*)d_in[3];
    const float* pab  = (const float*)d_in[4];
    float* ws  = (float*)d_ws;
    float* out = (float*)d_out;

    int wb_ok = (ws_size >= (size_t)(WB_OFF + 294912 + 64) * 4) ? 1 : 0;

    hipLaunchKernelGGL(k_prep, dim3(7), dim3(512), 0, stream, pixw, pixb, paw, pab, ws, wb_ok);
    if (wb_ok)
        hipLaunchKernelGGL(k_n2<true>,  dim3(196), dim3(512), 0, stream, x, paw, pab, ws);
    else
        hipLaunchKernelGGL(k_n2<false>, dim3(196), dim3(512), 0, stream, x, paw, pab, ws);
    hipLaunchKernelGGL(k_dj,    dim3(98),  dim3(256), 0, stream, x, ws);
    hipLaunchKernelGGL(k_pixel, dim3(784), dim3(256), 0, stream, x, ws);
    hipLaunchKernelGGL(k_log,   dim3(1),   dim3(256), 0, stream, ws, out);
}

// Round 3
// 75.075 us; speedup vs baseline: 1.9051x; 1.3709x over previous
//
#include <hip/hip_runtime.h>
#include <math.h>

#define EPS 1e-8f
#define NPATCH 196
#define HW 50176
#define LOG2E 1.4426950408889634f

// ws float offsets
#define GRAM_OFF 0        // 10
#define C_OFF 12          // 4
#define N2_OFF 64         // 784 (fallback path only)
#define M_OFF 1024        // 768*4
#define GQ_OFF 4096       // 784*4
#define PART_OFF 8192     // 784
#define NP2_OFF 9216      // 48*784
#define WA_OFF 65536      // bf16[768*768] = 294912 float slots
#define XPB_OFF 360448    // bf16[784*768] = 301056 float slots
#define WS_NEED ((size_t)(XPB_OFF + 301056 + 64) * 4)

typedef __attribute__((ext_vector_type(8))) short short8;
typedef __attribute__((ext_vector_type(4))) float f32x4;

static __device__ __forceinline__ unsigned short f2bf(float f) {
    unsigned u = __float_as_uint(f);
    u += 0x8000u + ((u >> 16) & 1u);     // RNE
    return (unsigned short)(u >> 16);
}

// blocks 0..11 : M[4][768] + WA bf16 conversion (k-chunks of 64)
// block  12    : gram(10) + c(4)
// blocks 13..208: gather x-patches -> XPB bf16 [784][768]
__global__ __launch_bounds__(512) void k_prep(const float* __restrict__ x,
                                              const float* __restrict__ pixw,
                                              const float* __restrict__ pixb,
                                              const float* __restrict__ paw,
                                              const float* __restrict__ pab,
                                              float* __restrict__ ws, int do_wb) {
    __shared__ float lds[2048];
    int t = threadIdx.x;
    int bid = blockIdx.x;
    if (bid < 12) {
        int lane = t & 63;
        int dh = t >> 6;                  // 0..7, wave-uniform
        int k = bid * 64 + lane;
        float m0 = 0.f, m1 = 0.f, m2 = 0.f, m3 = 0.f;
        unsigned short* wa = (unsigned short*)(ws + WA_OFF);
        #pragma unroll 4
        for (int i = 0; i < 96; ++i) {
            int d = dh * 96 + i;
            float w = paw[(size_t)d * 768 + k];
            float s0 = pixw[d*3+0], s1 = pixw[d*3+1], s2 = pixw[d*3+2], s3 = pixb[d];
            m0 = fmaf(s0, w, m0); m1 = fmaf(s1, w, m1);
            m2 = fmaf(s2, w, m2); m3 = fmaf(s3, w, m3);
            if (do_wb) wa[(size_t)d * 768 + k] = f2bf(w);
        }
        float* L = lds + (dh * 64 + lane) * 4;
        L[0] = m0; L[1] = m1; L[2] = m2; L[3] = m3;
        __syncthreads();
        if (t < 64) {
            float4 o = make_float4(0.f, 0.f, 0.f, 0.f);
            #pragma unroll
            for (int g = 0; g < 8; ++g) {
                const float* p = lds + (g * 64 + t) * 4;
                o.x += p[0]; o.y += p[1]; o.z += p[2]; o.w += p[3];
            }
            *(float4*)&ws[M_OFF + (bid * 64 + t) * 4] = o;
        }
    } else if (bid == 12) {
        float g[14];
        #pragma unroll
        for (int j = 0; j < 14; ++j) g[j] = 0.f;
        for (int d = t; d < 768; d += 512) {
            float w0 = pixw[d*3+0], w1 = pixw[d*3+1], w2 = pixw[d*3+2];
            float b = pixb[d], pb = pab[d];
            g[0] = fmaf(w0, w0, g[0]); g[1] = fmaf(w0, w1, g[1]);
            g[2] = fmaf(w0, w2, g[2]); g[3] = fmaf(w0, b,  g[3]);
            g[4] = fmaf(w1, w1, g[4]); g[5] = fmaf(w1, w2, g[5]);
            g[6] = fmaf(w1, b,  g[6]); g[7] = fmaf(w2, w2, g[7]);
            g[8] = fmaf(w2, b,  g[8]); g[9] = fmaf(b,  b,  g[9]);
            g[10] = fmaf(w0, pb, g[10]); g[11] = fmaf(w1, pb, g[11]);
            g[12] = fmaf(w2, pb, g[12]); g[13] = fmaf(b,  pb, g[13]);
        }
        #pragma unroll
        for (int off = 32; off; off >>= 1)
            #pragma unroll
            for (int j = 0; j < 14; ++j) g[j] += __shfl_down(g[j], off);
        int wv = t >> 6, ln = t & 63;
        if (ln == 0)
            for (int j = 0; j < 14; ++j) lds[wv * 14 + j] = g[j];
        __syncthreads();
        if (t < 14) {
            float s = 0.f;
            for (int w = 0; w < 8; ++w) s += lds[w * 14 + t];
            if (t < 10) ws[GRAM_OFF + t] = s;
            else        ws[C_OFF + (t - 10)] = s;
        }
    } else {
        if (!do_wb) return;
        int gb = bid - 13;
        unsigned short* xpb = (unsigned short*)(ws + XPB_OFF);
        #pragma unroll
        for (int j = 0; j < 6; ++j) {
            int flat = j * 512 + t;
            int p = flat / 768, e = flat - p * 768;
            int gp = gb * 4 + p;
            int b = gp / NPATCH, m = gp - b * NPATCH;
            int hp = m / 14, wq = m - hp * 14;
            int c = e >> 8, rem = e & 255, pr = rem >> 4, q = rem & 15;
            float v = x[((b * 3 + c) * 224 + hp * 16 + pr) * 224 + wq * 16 + q];
            xpb[(size_t)gp * 768 + e] = f2bf(v);
        }
    }
}

// 588 blocks x 256 thr (4 waves). wave -> one 16x16 C tile; K=768 in 24 MFMA.
// NP2[mtile][patch] = sum over this tile's 16 dims of (C + bias)^2.
__global__ __launch_bounds__(256) void k_gemm(const float* __restrict__ pab,
                                              float* __restrict__ ws) {
    const unsigned short* WA  = (const unsigned short*)(ws + WA_OFF);
    const unsigned short* XPB = (const unsigned short*)(ws + XPB_OFF);
    int t = threadIdx.x;
    int lane = t & 63;
    int wv = t >> 6;
    int bid = blockIdx.x;
    int msup = bid / 49;
    int ntile = bid - msup * 49;
    int mtile = msup * 4 + wv;
    int m0 = mtile * 16, n0 = ntile * 16;
    int ra = lane & 15, kg = lane >> 4;
    const short8* pa = (const short8*)(WA  + (size_t)(m0 + ra) * 768 + kg * 8);
    const short8* pb = (const short8*)(XPB + (size_t)(n0 + ra) * 768 + kg * 8);
    f32x4 acc = {0.f, 0.f, 0.f, 0.f};
    #pragma unroll 6
    for (int kk = 0; kk < 24; ++kk) {
        short8 a = pa[kk * 4];
        short8 b = pb[kk * 4];
        acc = __builtin_amdgcn_mfma_f32_16x16x32_bf16(a, b, acc, 0, 0, 0);
    }
    // C[row][col]: col = lane&15 (patch), row = kg*4 + i (dim within tile)
    float sq = 0.f;
    #pragma unroll
    for (int i = 0; i < 4; ++i) {
        float v = acc[i] + pab[m0 + kg * 4 + i];
        sq = fmaf(v, v, sq);
    }
    sq += __shfl_down(sq, 32);
    sq += __shfl_down(sq, 16);
    if (lane < 16)
        ws[NP2_OFF + (size_t)mtile * 784 + n0 + lane] = sq;
}

// fallback f32 norm path (only if ws too small for bf16 buffers)
__global__ __launch_bounds__(512, 2) void k_n2_fb(const float* __restrict__ x,
                                                  const float* __restrict__ paw,
                                                  const float* __restrict__ pab,
                                                  float* __restrict__ ws) {
    __shared__ float lds[4 * 64 * 13];
    __shared__ float red2[4][4];
    int t = threadIdx.x;
    int lane = t & 63;
    int wv = __builtin_amdgcn_readfirstlane(t >> 6);
    int dw = wv & 3, kh = wv >> 2;
    int pg = blockIdx.x;
    const float* xbp[4];
    #pragma unroll
    for (int pp = 0; pp < 4; ++pp) {
        int gp = pg * 4 + pp;
        int b = gp / NPATCH, m = gp - b * NPATCH;
        int hp = m / 14, wq = m - hp * 14;
        xbp[pp] = x + (size_t)b * (3 * HW) + (hp * 16) * 224 + wq * 16;
    }
    int d0 = dw * 192 + lane;
    float acc[3][4];
    #pragma unroll
    for (int i = 0; i < 3; ++i)
        #pragma unroll
        for (int p = 0; p < 4; ++p) acc[i][p] = 0.f;
    int r0 = kh * 24;
    #pragma unroll 2
    for (int r = r0; r < r0 + 24; ++r) {
        int c = r >> 4, pr = r & 15, kb = r * 16;
        #pragma unroll
        for (int qh = 0; qh < 2; ++qh) {
            float wf[3][8];
            #pragma unroll
            for (int dd = 0; dd < 3; ++dd) {
                const float* wrow = paw + (size_t)(d0 + dd * 64) * 768 + kb + qh * 8;
                float4 a = *(const float4*)(wrow);
                float4 b2 = *(const float4*)(wrow + 4);
                wf[dd][0] = a.x; wf[dd][1] = a.y; wf[dd][2] = a.z; wf[dd][3] = a.w;
                wf[dd][4] = b2.x; wf[dd][5] = b2.y; wf[dd][6] = b2.z; wf[dd][7] = b2.w;
            }
            #pragma unroll
            for (int q = 0; q < 8; ++q) {
                #pragma unroll
                for (int p = 0; p < 4; ++p) {
                    float xv = xbp[p][c * HW + pr * 224 + qh * 8 + q];
                    #pragma unroll
                    for (int dd = 0; dd < 3; ++dd)
                        acc[dd][p] = fmaf(wf[dd][q], xv, acc[dd][p]);
                }
            }
        }
    }
    if (kh == 1) {
        float* L = lds + (dw * 64 + lane) * 13;
        #pragma unroll
        for (int i = 0; i < 3; ++i)
            #pragma unroll
            for (int p = 0; p < 4; ++p) L[i * 4 + p] = acc[i][p];
    }
    __syncthreads();
    if (kh == 0) {
        const float* L = lds + (dw * 64 + lane) * 13;
        float sq[4] = {0.f, 0.f, 0.f, 0.f};
        #pragma unroll
        for (int i = 0; i < 3; ++i) {
            float bias = pab[d0 + i * 64];
            #pragma unroll
            for (int p = 0; p < 4; ++p) {
                float v = acc[i][p] + L[i * 4 + p] + bias;
                sq[p] = fmaf(v, v, sq[p]);
            }
        }
        #pragma unroll
        for (int off = 32; off; off >>= 1)
            #pragma unroll
            for (int p = 0; p < 4; ++p) sq[p] += __shfl_down(sq[p], off);
        if (lane == 0)
            for (int p = 0; p < 4; ++p) red2[dw][p] = sq[p];
    }
    __syncthreads();
    if (t < 4)
        ws[N2_OFF + pg * 4 + t] = red2[0][t] + red2[1][t] + red2[2][t] + red2[3][t];
}

// 98 blocks x 256: 8 patches/block, 32 lanes/patch: Gq = (M.x + c)/||q||
template<bool GEMM>
__global__ __launch_bounds__(256) void k_dj(const float* __restrict__ x,
                                            float* __restrict__ ws) {
    int t = threadIdx.x;
    int p8 = t >> 5, l = t & 31;
    int gp = blockIdx.x * 8 + p8;
    int b = gp / NPATCH, m = gp - b * NPATCH;
    int hp = m / 14, wq = m - hp * 14;
    const float* xb = x + (size_t)b * (3 * HW) + (hp * 16) * 224 + wq * 16;
    float d0 = 0.f, d1 = 0.f, d2 = 0.f, d3 = 0.f;
    #pragma unroll 4
    for (int j = 0; j < 24; ++j) {
        int k = j * 32 + l;
        int c = k >> 8, pr = (k >> 4) & 15, q = k & 15;
        float xv = xb[c * HW + pr * 224 + q];
        float4 Mv = *(const float4*)&ws[M_OFF + k * 4];
        d0 = fmaf(Mv.x, xv, d0); d1 = fmaf(Mv.y, xv, d1);
        d2 = fmaf(Mv.z, xv, d2); d3 = fmaf(Mv.w, xv, d3);
    }
    float n2p = 0.f;
    if (GEMM) {
        for (int i = l; i < 48; i += 32) n2p += ws[NP2_OFF + (size_t)i * 784 + gp];
    }
    #pragma unroll
    for (int off = 16; off; off >>= 1) {
        d0 += __shfl_down(d0, off, 32); d1 += __shfl_down(d1, off, 32);
        d2 += __shfl_down(d2, off, 32); d3 += __shfl_down(d3, off, 32);
        n2p += __shfl_down(n2p, off, 32);
    }
    if (l == 0) {
        float n2 = GEMM ? n2p : ws[N2_OFF + gp];
        float rq = 1.0f / fmaxf(sqrtf(n2), EPS);
        float4 o;
        o.x = (d0 + ws[C_OFF + 0]) * rq;
        o.y = (d1 + ws[C_OFF + 1]) * rq;
        o.z = (d2 + ws[C_OFF + 2]) * rq;
        o.w = (d3 + ws[C_OFF + 3]) * rq;
        *(float4*)&ws[GQ_OFF + gp * 4] = o;
    }
}

__global__ __launch_bounds__(256) void k_pixel(const float* __restrict__ x,
                                               float* __restrict__ ws) {
    int t = threadIdx.x;
    int bid = blockIdx.x;
    int b = bid / NPATCH, loc = bid - b * NPATCH;
    int hw = loc * 256 + t;
    const float* xb = x + (size_t)b * (3 * HW);
    float c0 = xb[hw], c1 = xb[hw + HW], c2 = xb[hw + 2 * HW];

    float G0 = ws[0], G1 = ws[1], G2 = ws[2], G3 = ws[3], G4 = ws[4];
    float G5 = ws[5], G6 = ws[6], G7 = ws[7], G8 = ws[8], G9 = ws[9];
    float n2 = G9;
    n2 = fmaf(G0, c0 * c0, n2);
    n2 = fmaf(G4, c1 * c1, n2);
    n2 = fmaf(G7, c2 * c2, n2);
    float cross = fmaf(G1, c0 * c1, fmaf(G2, c0 * c2, fmaf(G5, c1 * c2,
                  fmaf(G3, c0, fmaf(G6, c1, G8 * c2)))));
    n2 = fmaf(2.0f, cross, n2);

    float rnp = 1.0f / fmaxf(sqrtf(n2), EPS);
    float es = 2.0f * rnp * LOG2E;
    float a0 = c0 * es, a1 = c1 * es, a2 = c2 * es;

    const float4* gq = (const float4*)(ws + GQ_OFF) + b * NPATCH;
    float sum = 0.0f;
    #pragma unroll 4
    for (int m = 0; m < NPATCH; ++m) {
        float4 g = gq[m];
        float tt = fmaf(a0, g.x, fmaf(a1, g.y, fmaf(a2, g.z, es * g.w)));
        sum += __builtin_amdgcn_exp2f(tt);
    }
    {
        int ne = hw % NPATCH;
        float4 g = gq[ne];
        float tt = fmaf(a0, g.x, fmaf(a1, g.y, fmaf(a2, g.z, es * g.w)));
        sum -= __builtin_amdgcn_exp2f(tt);
    }

    #pragma unroll
    for (int off = 32; off; off >>= 1) sum += __shfl_down(sum, off);
    __shared__ float red[4];
    int wvv = t >> 6, ln = t & 63;
    if (ln == 0) red[wvv] = sum;
    __syncthreads();
    if (t == 0) ws[PART_OFF + bid] = red[0] + red[1] + red[2] + red[3];
}

__global__ __launch_bounds__(256) void k_log(const float* __restrict__ ws,
                                             float* __restrict__ out) {
    int t = threadIdx.x;
    float sum = 0.0f;
    for (int j = t; j < 784; j += 256) sum += ws[PART_OFF + j];
    #pragma unroll
    for (int off = 32; off; off >>= 1) sum += __shfl_down(sum, off);
    __shared__ float red[4];
    int wv = t >> 6, ln = t & 63;
    if (ln == 0) red[wv] = sum;
    __syncthreads();
    if (t == 0) out[0] = logf(red[0] + red[1] + red[2] + red[3]);
}

extern "C" void kernel_launch(void* const* d_in, const int* in_sizes, int n_in,
                              void* d_out, int out_size, void* d_ws, size_t ws_size,
                              hipStream_t stream) {
    (void)in_sizes; (void)n_in; (void)out_size;
    const float* x    = (const float*)d_in[0];
    const float* pixw = (const float*)d_in[1];
    const float* pixb = (const float*)d_in[2];
    const float* paw  = (const float*)d_in[3];
    const float* pab  = (const float*)d_in[4];
    float* ws  = (float*)d_ws;
    float* out = (float*)d_out;

    int ok = (ws_size >= WS_NEED) ? 1 : 0;

    hipLaunchKernelGGL(k_prep, dim3(209), dim3(512), 0, stream,
                       x, pixw, pixb, paw, pab, ws, ok);
    if (ok) {
        hipLaunchKernelGGL(k_gemm,     dim3(588), dim3(256), 0, stream, pab, ws);
        hipLaunchKernelGGL(k_dj<true>, dim3(98),  dim3(256), 0, stream, x, ws);
    } else {
        hipLaunchKernelGGL(k_n2_fb,     dim3(196), dim3(512), 0, stream, x, paw, pab, ws);
        hipLaunchKernelGGL(k_dj<false>, dim3(98),  dim3(256), 0, stream, x, ws);
    }
    hipLaunchKernelGGL(k_pixel, dim3(784), dim3(256), 0, stream, x, ws);
    hipLaunchKernelGGL(k_log,   dim3(1),   dim3(256), 0, stream, ws, out);
}

// Round 4
// 51.163 us; speedup vs baseline: 2.7955x; 1.4674x over previous
//
#include <hip/hip_runtime.h>
#include <math.h>

#define EPS 1e-8f
#define NPATCH 196
#define HW 50176
#define LOG2E 1.4426950408889634f

// ws float offsets — main path
#define GRAM_OFF 0        // 10
#define P5_OFF 64         // 48*784        (norm^2 partials)   [mtile][patch]
#define DJ_OFF 38400      // 48*784*4      (basis-dot partials)[mtile][patch][4]
#define GQ_OFF 188928     // 784*4
#define PART_OFF 192064   // 784
#define WA_OFF 196608     // bf16[768*768] = 294912 float slots
#define XPB_OFF 491520    // bf16[784*768] = 301056 float slots
#define WS_NEED ((size_t)(XPB_OFF + 301056 + 64) * 4)
// fallback-only offsets (never coexist with P5/DJ use)
#define C_OFF 12          // 4
#define N2_OFF 64         // 784
#define M_OFF 1024        // 768*4

typedef __attribute__((ext_vector_type(8))) short short8;
typedef __attribute__((ext_vector_type(4))) float f32x4;

static __device__ __forceinline__ unsigned short f2bf(float f) {
    unsigned u = __float_as_uint(f);
    u += 0x8000u + ((u >> 16) & 1u);     // RNE
    return (unsigned short)(u >> 16);
}

// ---------------- main-path prep: pure streaming ----------------
// blocks 0..287   : WA = bf16(paw), 8 elems/thread
// blocks 288..581 : XPB = bf16(gathered x-patches), 8 elems/thread
// block 582       : gram (10 floats)
__global__ __launch_bounds__(256) void k_prep(const float* __restrict__ x,
                                              const float* __restrict__ pixw,
                                              const float* __restrict__ pixb,
                                              const float* __restrict__ paw,
                                              float* __restrict__ ws) {
    int t = threadIdx.x;
    int bid = blockIdx.x;
    if (bid < 288) {
        int f8 = bid * 256 + t;                    // 0..73727
        const float4* src = (const float4*)paw + (size_t)f8 * 2;
        float4 a = src[0], b = src[1];
        short8 o;
        o[0] = f2bf(a.x); o[1] = f2bf(a.y); o[2] = f2bf(a.z); o[3] = f2bf(a.w);
        o[4] = f2bf(b.x); o[5] = f2bf(b.y); o[6] = f2bf(b.z); o[7] = f2bf(b.w);
        *(short8*)((unsigned short*)(ws + WA_OFF) + (size_t)f8 * 8) = o;
    } else if (bid < 582) {
        int f8 = (bid - 288) * 256 + t;            // 0..75263
        int gp = f8 / 96;                          // 96 8-chunks per patch
        int e = (f8 - gp * 96) * 8;
        int b = gp / NPATCH, m = gp - b * NPATCH;
        int hp = m / 14, wq = m - hp * 14;
        int c = e >> 8, rem = e & 255, pr = rem >> 4, q0 = rem & 15;
        const float* src = x + ((size_t)(b * 3 + c) * 224 + hp * 16 + pr) * 224
                             + wq * 16 + q0;
        float4 a = *(const float4*)src;
        float4 b2 = *(const float4*)(src + 4);
        short8 o;
        o[0] = f2bf(a.x); o[1] = f2bf(a.y); o[2] = f2bf(a.z); o[3] = f2bf(a.w);
        o[4] = f2bf(b2.x); o[5] = f2bf(b2.y); o[6] = f2bf(b2.z); o[7] = f2bf(b2.w);
        *(short8*)((unsigned short*)(ws + XPB_OFF) + (size_t)gp * 768 + e) = o;
    } else {
        __shared__ float lds[4 * 10];
        float g[10];
        #pragma unroll
        for (int j = 0; j < 10; ++j) g[j] = 0.f;
        #pragma unroll
        for (int dd = 0; dd < 3; ++dd) {
            int d = t + dd * 256;
            float w0 = pixw[d*3+0], w1 = pixw[d*3+1], w2 = pixw[d*3+2], b = pixb[d];
            g[0] = fmaf(w0, w0, g[0]); g[1] = fmaf(w0, w1, g[1]);
            g[2] = fmaf(w0, w2, g[2]); g[3] = fmaf(w0, b,  g[3]);
            g[4] = fmaf(w1, w1, g[4]); g[5] = fmaf(w1, w2, g[5]);
            g[6] = fmaf(w1, b,  g[6]); g[7] = fmaf(w2, w2, g[7]);
            g[8] = fmaf(w2, b,  g[8]); g[9] = fmaf(b,  b,  g[9]);
        }
        #pragma unroll
        for (int off = 32; off; off >>= 1)
            #pragma unroll
            for (int j = 0; j < 10; ++j) g[j] += __shfl_down(g[j], off);
        int wv = t >> 6, ln = t & 63;
        if (ln == 0)
            for (int j = 0; j < 10; ++j) lds[wv * 10 + j] = g[j];
        __syncthreads();
        if (t < 10)
            ws[GRAM_OFF + t] = lds[t] + lds[10 + t] + lds[20 + t] + lds[30 + t];
    }
}

// 588 blocks x 256 thr (4 waves). wave -> one 16x16 C tile; K=768 in 24 MFMA.
// Emits per-tile partials: P5 (sum v^2) and DJ[4] (sum basis_j * v).
__global__ __launch_bounds__(256) void k_gemm(const float* __restrict__ pixw,
                                              const float* __restrict__ pixb,
                                              const float* __restrict__ pab,
                                              float* __restrict__ ws) {
    const unsigned short* WA  = (const unsigned short*)(ws + WA_OFF);
    const unsigned short* XPB = (const unsigned short*)(ws + XPB_OFF);
    int t = threadIdx.x;
    int lane = t & 63;
    int wv = t >> 6;
    int bid = blockIdx.x;
    int msup = bid / 49;
    int ntile = bid - msup * 49;
    int mtile = msup * 4 + wv;
    int m0 = mtile * 16, n0 = ntile * 16;
    int ra = lane & 15, kg = lane >> 4;
    const short8* pa = (const short8*)(WA  + (size_t)(m0 + ra) * 768 + kg * 8);
    const short8* pb = (const short8*)(XPB + (size_t)(n0 + ra) * 768 + kg * 8);
    f32x4 acc = {0.f, 0.f, 0.f, 0.f};
    #pragma unroll 6
    for (int kk = 0; kk < 24; ++kk) {
        short8 a = pa[kk * 4];
        short8 b = pb[kk * 4];
        acc = __builtin_amdgcn_mfma_f32_16x16x32_bf16(a, b, acc, 0, 0, 0);
    }
    // C[row][col]: col = lane&15 (patch), row = kg*4 + i (dim within tile)
    float sq = 0.f, d0 = 0.f, d1 = 0.f, d2 = 0.f, d3 = 0.f;
    #pragma unroll
    for (int i = 0; i < 4; ++i) {
        int d = m0 + kg * 4 + i;
        float v = acc[i] + pab[d];
        sq = fmaf(v, v, sq);
        d0 = fmaf(pixw[d*3+0], v, d0);
        d1 = fmaf(pixw[d*3+1], v, d1);
        d2 = fmaf(pixw[d*3+2], v, d2);
        d3 = fmaf(pixb[d],     v, d3);
    }
    sq += __shfl_down(sq, 32); d0 += __shfl_down(d0, 32);
    d1 += __shfl_down(d1, 32); d2 += __shfl_down(d2, 32);
    d3 += __shfl_down(d3, 32);
    sq += __shfl_down(sq, 16); d0 += __shfl_down(d0, 16);
    d1 += __shfl_down(d1, 16); d2 += __shfl_down(d2, 16);
    d3 += __shfl_down(d3, 16);
    if (lane < 16) {
        int gp = n0 + lane;
        ws[P5_OFF + (size_t)mtile * 784 + gp] = sq;
        *(float4*)&ws[DJ_OFF + ((size_t)mtile * 784 + gp) * 4] =
            make_float4(d0, d1, d2, d3);
    }
}

// 49 blocks x 256: 16 patches/block, 16 lanes/patch. Gq = dj / ||v||.
__global__ __launch_bounds__(256) void k_final(float* __restrict__ ws) {
    int t = threadIdx.x;
    int pl = t >> 4, l = t & 15;
    int gp = blockIdx.x * 16 + pl;
    float n2 = 0.f, d0 = 0.f, d1 = 0.f, d2 = 0.f, d3 = 0.f;
    #pragma unroll
    for (int r = 0; r < 3; ++r) {
        int i = l + r * 16;
        n2 += ws[P5_OFF + (size_t)i * 784 + gp];
        float4 dv = *(const float4*)&ws[DJ_OFF + ((size_t)i * 784 + gp) * 4];
        d0 += dv.x; d1 += dv.y; d2 += dv.z; d3 += dv.w;
    }
    #pragma unroll
    for (int off = 8; off; off >>= 1) {
        n2 += __shfl_down(n2, off, 16);
        d0 += __shfl_down(d0, off, 16); d1 += __shfl_down(d1, off, 16);
        d2 += __shfl_down(d2, off, 16); d3 += __shfl_down(d3, off, 16);
    }
    if (l == 0) {
        float rq = 1.0f / fmaxf(sqrtf(n2), EPS);
        *(float4*)&ws[GQ_OFF + gp * 4] = make_float4(d0*rq, d1*rq, d2*rq, d3*rq);
    }
}

__global__ __launch_bounds__(256) void k_pixel(const float* __restrict__ x,
                                               float* __restrict__ ws) {
    int t = threadIdx.x;
    int bid = blockIdx.x;
    int b = bid / NPATCH, loc = bid - b * NPATCH;
    int hw = loc * 256 + t;
    const float* xb = x + (size_t)b * (3 * HW);
    float c0 = xb[hw], c1 = xb[hw + HW], c2 = xb[hw + 2 * HW];

    float G0 = ws[0], G1 = ws[1], G2 = ws[2], G3 = ws[3], G4 = ws[4];
    float G5 = ws[5], G6 = ws[6], G7 = ws[7], G8 = ws[8], G9 = ws[9];
    float n2 = G9;
    n2 = fmaf(G0, c0 * c0, n2);
    n2 = fmaf(G4, c1 * c1, n2);
    n2 = fmaf(G7, c2 * c2, n2);
    float cross = fmaf(G1, c0 * c1, fmaf(G2, c0 * c2, fmaf(G5, c1 * c2,
                  fmaf(G3, c0, fmaf(G6, c1, G8 * c2)))));
    n2 = fmaf(2.0f, cross, n2);

    float rnp = 1.0f / fmaxf(sqrtf(n2), EPS);
    float es = 2.0f * rnp * LOG2E;
    float a0 = c0 * es, a1 = c1 * es, a2 = c2 * es;

    const float4* gq = (const float4*)(ws + GQ_OFF) + b * NPATCH;
    float sum = 0.0f;
    #pragma unroll 4
    for (int m = 0; m < NPATCH; ++m) {
        float4 g = gq[m];
        float tt = fmaf(a0, g.x, fmaf(a1, g.y, fmaf(a2, g.z, es * g.w)));
        sum += __builtin_amdgcn_exp2f(tt);
    }
    {
        int ne = hw % NPATCH;
        float4 g = gq[ne];
        float tt = fmaf(a0, g.x, fmaf(a1, g.y, fmaf(a2, g.z, es * g.w)));
        sum -= __builtin_amdgcn_exp2f(tt);
    }

    #pragma unroll
    for (int off = 32; off; off >>= 1) sum += __shfl_down(sum, off);
    __shared__ float red[4];
    int wvv = t >> 6, ln = t & 63;
    if (ln == 0) red[wvv] = sum;
    __syncthreads();
    if (t == 0) ws[PART_OFF + bid] = red[0] + red[1] + red[2] + red[3];
}

__global__ __launch_bounds__(256) void k_log(const float* __restrict__ ws,
                                             float* __restrict__ out) {
    int t = threadIdx.x;
    float sum = 0.0f;
    for (int j = t; j < 784; j += 256) sum += ws[PART_OFF + j];
    #pragma unroll
    for (int off = 32; off; off >>= 1) sum += __shfl_down(sum, off);
    __shared__ float red[4];
    int wv = t >> 6, ln = t & 63;
    if (ln == 0) red[wv] = sum;
    __syncthreads();
    if (t == 0) out[0] = logf(red[0] + red[1] + red[2] + red[3]);
}

// ---------------- fallback path (tiny ws): M + c, f32 norms ----------------
__global__ __launch_bounds__(512) void k_prep_fb(const float* __restrict__ pixw,
                                                 const float* __restrict__ pixb,
                                                 const float* __restrict__ paw,
                                                 const float* __restrict__ pab,
                                                 float* __restrict__ ws) {
    __shared__ float lds[2048];
    int t = threadIdx.x;
    int bid = blockIdx.x;
    if (bid < 12) {
        int lane = t & 63;
        int dh = t >> 6;
        int k = bid * 64 + lane;
        float m0 = 0.f, m1 = 0.f, m2 = 0.f, m3 = 0.f;
        #pragma unroll 4
        for (int i = 0; i < 96; ++i) {
            int d = dh * 96 + i;
            float w = paw[(size_t)d * 768 + k];
            m0 = fmaf(pixw[d*3+0], w, m0); m1 = fmaf(pixw[d*3+1], w, m1);
            m2 = fmaf(pixw[d*3+2], w, m2); m3 = fmaf(pixb[d], w, m3);
        }
        float* L = lds + (dh * 64 + lane) * 4;
        L[0] = m0; L[1] = m1; L[2] = m2; L[3] = m3;
        __syncthreads();
        if (t < 64) {
            float4 o = make_float4(0.f, 0.f, 0.f, 0.f);
            #pragma unroll
            for (int g = 0; g < 8; ++g) {
                const float* p = lds + (g * 64 + t) * 4;
                o.x += p[0]; o.y += p[1]; o.z += p[2]; o.w += p[3];
            }
            *(float4*)&ws[M_OFF + (bid * 64 + t) * 4] = o;
        }
    } else {
        float g[14];
        #pragma unroll
        for (int j = 0; j < 14; ++j) g[j] = 0.f;
        for (int d = t; d < 768; d += 512) {
            float w0 = pixw[d*3+0], w1 = pixw[d*3+1], w2 = pixw[d*3+2];
            float b = pixb[d], pb = pab[d];
            g[0] = fmaf(w0, w0, g[0]); g[1] = fmaf(w0, w1, g[1]);
            g[2] = fmaf(w0, w2, g[2]); g[3] = fmaf(w0, b,  g[3]);
            g[4] = fmaf(w1, w1, g[4]); g[5] = fmaf(w1, w2, g[5]);
            g[6] = fmaf(w1, b,  g[6]); g[7] = fmaf(w2, w2, g[7]);
            g[8] = fmaf(w2, b,  g[8]); g[9] = fmaf(b,  b,  g[9]);
            g[10] = fmaf(w0, pb, g[10]); g[11] = fmaf(w1, pb, g[11]);
            g[12] = fmaf(w2, pb, g[12]); g[13] = fmaf(b,  pb, g[13]);
        }
        #pragma unroll
        for (int off = 32; off; off >>= 1)
            #pragma unroll
            for (int j = 0; j < 14; ++j) g[j] += __shfl_down(g[j], off);
        int wv = t >> 6, ln = t & 63;
        if (ln == 0)
            for (int j = 0; j < 14; ++j) lds[wv * 14 + j] = g[j];
        __syncthreads();
        if (t < 14) {
            float s = 0.f;
            for (int w = 0; w < 8; ++w) s += lds[w * 14 + t];
            if (t < 10) ws[GRAM_OFF + t] = s;
            else        ws[C_OFF + (t - 10)] = s;
        }
    }
}

__global__ __launch_bounds__(512, 2) void k_n2_fb(const float* __restrict__ x,
                                                  const float* __restrict__ paw,
                                                  const float* __restrict__ pab,
                                                  float* __restrict__ ws) {
    __shared__ float lds[4 * 64 * 13];
    __shared__ float red2[4][4];
    int t = threadIdx.x;
    int lane = t & 63;
    int wv = __builtin_amdgcn_readfirstlane(t >> 6);
    int dw = wv & 3, kh = wv >> 2;
    int pg = blockIdx.x;
    const float* xbp[4];
    #pragma unroll
    for (int pp = 0; pp < 4; ++pp) {
        int gp = pg * 4 + pp;
        int b = gp / NPATCH, m = gp - b * NPATCH;
        int hp = m / 14, wq = m - hp * 14;
        xbp[pp] = x + (size_t)b * (3 * HW) + (hp * 16) * 224 + wq * 16;
    }
    int d0 = dw * 192 + lane;
    float acc[3][4];
    #pragma unroll
    for (int i = 0; i < 3; ++i)
        #pragma unroll
        for (int p = 0; p < 4; ++p) acc[i][p] = 0.f;
    int r0 = kh * 24;
    #pragma unroll 2
    for (int r = r0; r < r0 + 24; ++r) {
        int c = r >> 4, pr = r & 15, kb = r * 16;
        #pragma unroll
        for (int qh = 0; qh < 2; ++qh) {
            float wf[3][8];
            #pragma unroll
            for (int dd = 0; dd < 3; ++dd) {
                const float* wrow = paw + (size_t)(d0 + dd * 64) * 768 + kb + qh * 8;
                float4 a = *(const float4*)(wrow);
                float4 b2 = *(const float4*)(wrow + 4);
                wf[dd][0] = a.x; wf[dd][1] = a.y; wf[dd][2] = a.z; wf[dd][3] = a.w;
                wf[dd][4] = b2.x; wf[dd][5] = b2.y; wf[dd][6] = b2.z; wf[dd][7] = b2.w;
            }
            #pragma unroll
            for (int q = 0; q < 8; ++q) {
                #pragma unroll
                for (int p = 0; p < 4; ++p) {
                    float xv = xbp[p][c * HW + pr * 224 + qh * 8 + q];
                    #pragma unroll
                    for (int dd = 0; dd < 3; ++dd)
                        acc[dd][p] = fmaf(wf[dd][q], xv, acc[dd][p]);
                }
            }
        }
    }
    if (kh == 1) {
        float* L = lds + (dw * 64 + lane) * 13;
        #pragma unroll
        for (int i = 0; i < 3; ++i)
            #pragma unroll
            for (int p = 0; p < 4; ++p) L[i * 4 + p] = acc[i][p];
    }
    __syncthreads();
    if (kh == 0) {
        const float* L = lds + (dw * 64 + lane) * 13;
        float sq[4] = {0.f, 0.f, 0.f, 0.f};
        #pragma unroll
        for (int i = 0; i < 3; ++i) {
            float bias = pab[d0 + i * 64];
            #pragma unroll
            for (int p = 0; p < 4; ++p) {
                float v = acc[i][p] + L[i * 4 + p] + bias;
                sq[p] = fmaf(v, v, sq[p]);
            }
        }
        #pragma unroll
        for (int off = 32; off; off >>= 1)
            #pragma unroll
            for (int p = 0; p < 4; ++p) sq[p] += __shfl_down(sq[p], off);
        if (lane == 0)
            for (int p = 0; p < 4; ++p) red2[dw][p] = sq[p];
    }
    __syncthreads();
    if (t < 4)
        ws[N2_OFF + pg * 4 + t] = red2[0][t] + red2[1][t] + red2[2][t] + red2[3][t];
}

__global__ __launch_bounds__(256) void k_dj_fb(const float* __restrict__ x,
                                               float* __restrict__ ws) {
    int t = threadIdx.x;
    int p8 = t >> 5, l = t & 31;
    int gp = blockIdx.x * 8 + p8;
    int b = gp / NPATCH, m = gp - b * NPATCH;
    int hp = m / 14, wq = m - hp * 14;
    const float* xb = x + (size_t)b * (3 * HW) + (hp * 16) * 224 + wq * 16;
    float d0 = 0.f, d1 = 0.f, d2 = 0.f, d3 = 0.f;
    #pragma unroll 4
    for (int j = 0; j < 24; ++j) {
        int k = j * 32 + l;
        int c = k >> 8, pr = (k >> 4) & 15, q = k & 15;
        float xv = xb[c * HW + pr * 224 + q];
        float4 Mv = *(const float4*)&ws[M_OFF + k * 4];
        d0 = fmaf(Mv.x, xv, d0); d1 = fmaf(Mv.y, xv, d1);
        d2 = fmaf(Mv.z, xv, d2); d3 = fmaf(Mv.w, xv, d3);
    }
    #pragma unroll
    for (int off = 16; off; off >>= 1) {
        d0 += __shfl_down(d0, off, 32); d1 += __shfl_down(d1, off, 32);
        d2 += __shfl_down(d2, off, 32); d3 += __shfl_down(d3, off, 32);
    }
    if (l == 0) {
        float n2 = ws[N2_OFF + gp];
        float rq = 1.0f / fmaxf(sqrtf(n2), EPS);
        float4 o;
        o.x = (d0 + ws[C_OFF + 0]) * rq;
        o.y = (d1 + ws[C_OFF + 1]) * rq;
        o.z = (d2 + ws[C_OFF + 2]) * rq;
        o.w = (d3 + ws[C_OFF + 3]) * rq;
        *(float4*)&ws[GQ_OFF + gp * 4] = o;
    }
}

extern "C" void kernel_launch(void* const* d_in, const int* in_sizes, int n_in,
                              void* d_out, int out_size, void* d_ws, size_t ws_size,
                              hipStream_t stream) {
    (void)in_sizes; (void)n_in; (void)out_size;
    const float* x    = (const float*)d_in[0];
    const float* pixw = (const float*)d_in[1];
    const float* pixb = (const float*)d_in[2];
    const float* paw  = (const float*)d_in[3];
    const float* pab  = (const float*)d_in[4];
    float* ws  = (float*)d_ws;
    float* out = (float*)d_out;

    if (ws_size >= WS_NEED) {
        hipLaunchKernelGGL(k_prep,  dim3(583), dim3(256), 0, stream, x, pixw, pixb, paw, ws);
        hipLaunchKernelGGL(k_gemm,  dim3(588), dim3(256), 0, stream, pixw, pixb, pab, ws);
        hipLaunchKernelGGL(k_final, dim3(49),  dim3(256), 0, stream, ws);
    } else {
        hipLaunchKernelGGL(k_prep_fb, dim3(13),  dim3(512), 0, stream, pixw, pixb, paw, pab, ws);
        hipLaunchKernelGGL(k_n2_fb,   dim3(196), dim3(512), 0, stream, x, paw, pab, ws);
        hipLaunchKernelGGL(k_dj_fb,   dim3(98),  dim3(256), 0, stream, x, ws);
    }
    hipLaunchKernelGGL(k_pixel, dim3(784), dim3(256), 0, stream, x, ws);
    hipLaunchKernelGGL(k_log,   dim3(1),   dim3(256), 0, stream, ws, out);
}